// Round 12
// baseline (59.914 us; speedup 1.0000x reference)
//
#include <hip/hip_runtime.h>
#include <hip/hip_bf16.h>

#define ALPHA  0.2f
#define L2E    1.4426950408889634f

typedef __attribute__((ext_vector_type(8))) short  short8;
typedef __attribute__((ext_vector_type(4))) float  f32x4;
typedef unsigned short u16;

__device__ __forceinline__ u16 f2bf(float f) {
    union { __hip_bfloat16 h; u16 u; } v;
    v.h = __float2bfloat16(f);
    return v.u;
}
__device__ __forceinline__ unsigned pk2(float a, float b) {   // lo=a, hi=b
    union { __hip_bfloat162 h2; unsigned u; } v;
    float2 f2; f2.x = a; f2.y = b;
    v.h2 = __float22bfloat162_rn(f2);
    return v.u;
}
__device__ __forceinline__ float lrelu(float x) { return fmaxf(x, ALPHA * x); }

// ---- prep: W -> wfrag[pair 128][lane 64][8] (B-fragment-contiguous bf16),
//      pair = ks*16 + cblock; also w1 = W@a1, w2 = W@a2.
__global__ void prep(const float* __restrict__ W, const float* __restrict__ a1,
                     const float* __restrict__ a2, u16* __restrict__ wfrag,
                     float* __restrict__ w1, float* __restrict__ w2) {
    int b = blockIdx.x;
    if (b < 64) {
        int t    = threadIdx.x;
        int pair = b * 2 + (t >> 7);
        int l    = (t >> 1) & 63;
        int jh   = (t & 1) * 4;
        int ks   = pair >> 4, cb = pair & 15;
        int c  = cb * 16 + (l & 15);
        int k0 = ks * 32 + (l >> 4) * 8 + jh;
        ushort4 o;
        o.x = f2bf(W[(size_t)(k0 + 0) * 256 + c]);
        o.y = f2bf(W[(size_t)(k0 + 1) * 256 + c]);
        o.z = f2bf(W[(size_t)(k0 + 2) * 256 + c]);
        o.w = f2bf(W[(size_t)(k0 + 3) * 256 + c]);
        *(ushort4*)&wfrag[(size_t)pair * 512 + l * 8 + jh] = o;
    } else {
        int bb = b - 64;                       // 0..3
        int wv = threadIdx.x >> 6, lane = threadIdx.x & 63;
        for (int kk = 0; kk < 16; ++kk) {
            int k = bb * 64 + wv * 16 + kk;
            float4 wv4 = *(const float4*)(W + (size_t)k * 256 + 4 * lane);
            float4 a14 = *(const float4*)(a1 + 4 * lane);
            float4 a24 = *(const float4*)(a2 + 4 * lane);
            float d1 = wv4.x*a14.x + wv4.y*a14.y + wv4.z*a14.z + wv4.w*a14.w;
            float d2 = wv4.x*a24.x + wv4.y*a24.y + wv4.z*a24.z + wv4.w*a24.w;
            #pragma unroll
            for (int off = 32; off; off >>= 1) {
                d1 += __shfl_xor(d1, off);
                d2 += __shfl_xor(d2, off);
            }
            if (lane == 0) { w1[k] = d1; w2[k] = d2; }
        }
    }
}

// ======================= fused: LN + GEMM1 + softmax + PV ==================
// grid 256, 1024 threads = 16 waves/CU. s1s/s2s stored PRE-SCALED by L2E.
// PV accumulates UNNORMALIZED E@h; l[i] summed in-wave; scale 1/l at store.
__global__ __launch_bounds__(1024)
void gat(const int* __restrict__ item_seq, const float* __restrict__ emb,
         const float* __restrict__ pos, const float* __restrict__ gamma,
         const float* __restrict__ beta, const float* __restrict__ w1,
         const float* __restrict__ w2, const u16* __restrict__ wfrag,
         float* __restrict__ out)
{
    __shared__ u16 xb[256 * 256];            // 128 KB
    __shared__ __align__(16) float s1s[256], s2s[256];
    __shared__ float wmax[16];
    __shared__ float s2r;
    const int b    = blockIdx.x;
    const int tid  = threadIdx.x;
    const int lane = tid & 63, wid = tid >> 6, g = lane >> 4, li = lane & 15;
    const int iw_  = wid >> 2, nw = wid & 3;   // 4x4 wave grid (GEMM1)

    // ---- Phase A: gather + LN + s1/s2 (wave-per-row, 4 rows batched) ------
    {
        float4 g4  = *(const float4*)(gamma + 4 * lane);
        float4 b4  = *(const float4*)(beta  + 4 * lane);
        float4 w14 = *(const float4*)(w1    + 4 * lane);
        float4 w24 = *(const float4*)(w2    + 4 * lane);
        float4 u4, t4;
        u4.x = g4.x*w14.x; u4.y = g4.y*w14.y; u4.z = g4.z*w14.z; u4.w = g4.w*w14.w;
        t4.x = g4.x*w24.x; t4.y = g4.y*w24.y; t4.z = g4.z*w24.z; t4.w = g4.w*w24.w;
        float cA = u4.x + u4.y + u4.z + u4.w;                     // sum(gamma*w1)
        float cB = t4.x + t4.y + t4.z + t4.w;                     // sum(gamma*w2)
        float cC = b4.x*w14.x + b4.y*w14.y + b4.z*w14.z + b4.w*w14.w;  // beta.w1
        float cD = b4.x*w24.x + b4.y*w24.y + b4.z*w24.z + b4.w*w24.w;  // beta.w2
        #pragma unroll
        for (int off = 32; off; off >>= 1) {
            cA += __shfl_xor(cA, off); cB += __shfl_xor(cB, off);
            cC += __shfl_xor(cC, off); cD += __shfl_xor(cD, off);
        }
        float rm = -3.0e38f;
        for (int it = 0; it < 4; ++it) {
            int r0 = it * 64 + wid;
            int gI[4];
            #pragma unroll
            for (int m = 0; m < 4; ++m) gI[m] = item_seq[b * 256 + r0 + m * 16];
            float4 e[4], p[4];
            #pragma unroll
            for (int m = 0; m < 4; ++m)
                e[m] = *(const float4*)(emb + (size_t)gI[m] * 256 + 4 * lane);
            #pragma unroll
            for (int m = 0; m < 4; ++m)
                p[m] = *(const float4*)(pos + (size_t)(r0 + m * 16) * 256 + 4 * lane);
            float4 v[4]; float s[4], q[4], d1[4], d2[4];
            #pragma unroll
            for (int m = 0; m < 4; ++m) {
                float4 vv;
                vv.x = e[m].x + p[m].x; vv.y = e[m].y + p[m].y;
                vv.z = e[m].z + p[m].z; vv.w = e[m].w + p[m].w;
                v[m] = vv;
                s[m]  = vv.x + vv.y + vv.z + vv.w;
                q[m]  = vv.x*vv.x + vv.y*vv.y + vv.z*vv.z + vv.w*vv.w;
                d1[m] = vv.x*u4.x + vv.y*u4.y + vv.z*u4.z + vv.w*u4.w;
                d2[m] = vv.x*t4.x + vv.y*t4.y + vv.z*t4.z + vv.w*t4.w;
            }
            #pragma unroll
            for (int off = 32; off; off >>= 1) {   // one chain, ILP-16
                #pragma unroll
                for (int m = 0; m < 4; ++m) {
                    s[m]  += __shfl_xor(s[m],  off);
                    q[m]  += __shfl_xor(q[m],  off);
                    d1[m] += __shfl_xor(d1[m], off);
                    d2[m] += __shfl_xor(d2[m], off);
                }
            }
            #pragma unroll
            for (int m = 0; m < 4; ++m) {
                int r = r0 + m * 16;
                float mu  = s[m] * (1.0f/256.0f);
                float rs  = rsqrtf(q[m] * (1.0f/256.0f) - mu*mu + 1e-12f);
                float s1v = (rs * (d1[m] - mu * cA) + cC) * L2E;   // pre-scaled
                float s2v = (rs * (d2[m] - mu * cB) + cD) * L2E;
                if (lane == 0) { s1s[r] = s1v; s2s[r] = s2v; }
                rm = fmaxf(rm, s2v);
                uint2 o;
                o.x = pk2((v[m].x - mu) * rs * g4.x + b4.x,
                          (v[m].y - mu) * rs * g4.y + b4.y);
                o.y = pk2((v[m].z - mu) * rs * g4.z + b4.z,
                          (v[m].w - mu) * rs * g4.w + b4.w);
                int sl = (lane >> 1), sub = (lane & 1) * 4;
                *(uint2*)&xb[r * 256 + ((sl ^ (r & 7)) << 3) + sub] = o;
            }
        }
        if (lane == 0) wmax[wid] = rm;
    }
    __syncthreads();   // bar1: xb(x), s1s, s2s, wmax ready

    // thread 0 folds the block s2max while others start GEMM1 (published @bar2)
    if (tid == 0) {
        float m0 = wmax[0];
        #pragma unroll
        for (int k = 1; k < 16; ++k) m0 = fmaxf(m0, wmax[k]);
        s2r = m0;
    }

    // ---- GEMM1: h = x @ W; B-frags prefetched (ks+1 loads before ks MFMA) -
    f32x4 acc[4][4];
    #pragma unroll
    for (int mt = 0; mt < 4; ++mt)
        #pragma unroll
        for (int nt = 0; nt < 4; ++nt)
            acc[mt][nt] = (f32x4){0.f, 0.f, 0.f, 0.f};

    {
        short8 bf[4];
        #pragma unroll
        for (int nt = 0; nt < 4; ++nt)
            bf[nt] = *(const short8*)(wfrag
                       + ((size_t)(nw * 4 + nt) * 64 + lane) * 8);
        #pragma unroll
        for (int ks = 0; ks < 8; ++ks) {
            short8 bfn[4];
            if (ks < 7) {
                #pragma unroll
                for (int nt = 0; nt < 4; ++nt)
                    bfn[nt] = *(const short8*)(wfrag
                               + ((size_t)((ks + 1) * 16 + nw * 4 + nt) * 64 + lane) * 8);
            }
            #pragma unroll
            for (int mt = 0; mt < 4; ++mt) {
                int rl = iw_ * 64 + mt * 16 + li;
                short8 af = *(const short8*)&xb[rl * 256 + (((ks*4+g) ^ (rl & 7)) << 3)];
                #pragma unroll
                for (int nt = 0; nt < 4; ++nt)
                    acc[mt][nt] = __builtin_amdgcn_mfma_f32_16x16x32_bf16(
                        af, bf[nt], acc[mt][nt], 0, 0, 0);
            }
            if (ks < 7) {
                #pragma unroll
                for (int nt = 0; nt < 4; ++nt) bf[nt] = bfn[nt];
            }
        }
    }
    __syncthreads();   // bar2: all x reads done; s2r published

    // ---- transpose h into xb as hT[c][j] ----------------------------------
    #pragma unroll
    for (int mt = 0; mt < 4; ++mt)
        #pragma unroll
        for (int nt = 0; nt < 4; ++nt) {
            int c  = nw * 64 + nt * 16 + li;
            int i0 = iw_ * 64 + mt * 16 + 4 * g;
            uint2 o;
            o.x = pk2(acc[mt][nt][0], acc[mt][nt][1]);
            o.y = pk2(acc[mt][nt][2], acc[mt][nt][3]);
            *(uint2*)&xb[c * 256 + (((i0 >> 3) ^ (c & 7)) << 3) + (i0 & 7)] = o;
        }
    __syncthreads();   // bar3: hT ready

    // ---- PV: out = (E @ h) * (1/l); wave grid 8 (i) x 2 (c) ---------------
    {
        const int ig2 = wid >> 1;   // i-group: 32 rows
        const int ng2 = wid & 1;    // c-group: 128 cols
        f32x4 oacc[2][8];
        #pragma unroll
        for (int mt = 0; mt < 2; ++mt)
            #pragma unroll
            for (int nt = 0; nt < 8; ++nt)
                oacc[mt][nt] = (f32x4){0.f, 0.f, 0.f, 0.f};

        float s2m = s2r;
        float aBase[2], bBase[2], pl[2];
        #pragma unroll
        for (int mt = 0; mt < 2; ++mt) {
            int i = ig2 * 32 + mt * 16 + li;
            float s1v = s1s[i];
            float mi  = lrelu(s1v + s2m);
            aBase[mt] = s1v - mi;
            bBase[mt] = fmaf(ALPHA, s1v, -mi);
            pl[mt] = 0.f;
        }

        #pragma unroll
        for (int js = 0; js < 8; ++js) {
            float4 sv0 = *(const float4*)&s2s[js * 32 + g * 8];
            float4 sv1 = *(const float4*)&s2s[js * 32 + g * 8 + 4];
            float s2l[8] = {sv0.x, sv0.y, sv0.z, sv0.w, sv1.x, sv1.y, sv1.z, sv1.w};

            short8 pfr[2];
            #pragma unroll
            for (int mt = 0; mt < 2; ++mt) {
                union { unsigned int u[4]; short8 s; } pk;
                #pragma unroll
                for (int q2 = 0; q2 < 4; ++q2) {
                    float sA = s2l[2 * q2], sB = s2l[2 * q2 + 1];
                    float p0 = __builtin_amdgcn_exp2f(
                        fmaxf(aBase[mt] + sA, fmaf(ALPHA, sA, bBase[mt])));
                    float p1 = __builtin_amdgcn_exp2f(
                        fmaxf(aBase[mt] + sB, fmaf(ALPHA, sB, bBase[mt])));
                    pl[mt] += p0 + p1;
                    pk.u[q2] = pk2(p0, p1);
                }
                pfr[mt] = pk.s;
            }
            #pragma unroll
            for (int nt = 0; nt < 8; ++nt) {
                int cl = ng2 * 128 + nt * 16 + li;
                short8 vf = *(const short8*)&xb[cl * 256
                              + (((js * 4 + g) ^ (cl & 7)) << 3)];
                #pragma unroll
                for (int mt = 0; mt < 2; ++mt)
                    oacc[mt][nt] = __builtin_amdgcn_mfma_f32_16x16x32_bf16(
                        pfr[mt], vf, oacc[mt][nt], 0, 0, 0);
            }
        }

        // l[i]: in-wave g-reduction (lanes with same li across 4 g's)
        float linv[2][4];
        #pragma unroll
        for (int mt = 0; mt < 2; ++mt) {
            float t = pl[mt];
            t += __shfl_xor(t, 16);
            t += __shfl_xor(t, 32);
            #pragma unroll
            for (int q2 = 0; q2 < 4; ++q2)
                linv[mt][q2] = 1.0f / __shfl(t, 4 * g + q2);
        }

        size_t ob = (size_t)b * (256 * 256);
        #pragma unroll
        for (int mt = 0; mt < 2; ++mt)
            #pragma unroll
            for (int nt = 0; nt < 8; ++nt) {
                int c  = ng2 * 128 + nt * 16 + li;
                int i0 = ig2 * 32 + mt * 16 + 4 * g;
                #pragma unroll
                for (int q2 = 0; q2 < 4; ++q2)
                    out[ob + (size_t)(i0 + q2) * 256 + c] = oacc[mt][nt][q2] * linv[mt][q2];
            }
    }
}

extern "C" void kernel_launch(void* const* d_in, const int* in_sizes, int n_in,
                              void* d_out, int out_size, void* d_ws, size_t ws_size,
                              hipStream_t stream) {
    (void)in_sizes; (void)n_in; (void)out_size; (void)ws_size;
    const int*   seq   = (const int*)d_in[0];
    const float* emb   = (const float*)d_in[1];
    const float* pos   = (const float*)d_in[2];
    const float* W     = (const float*)d_in[3];
    const float* a1    = (const float*)d_in[4];
    const float* a2    = (const float*)d_in[5];
    const float* gamma = (const float*)d_in[6];
    const float* beta  = (const float*)d_in[7];

    char* ws = (char*)d_ws;
    u16*   wfrag = (u16*)ws;                     // 131072 B
    float* w1    = (float*)(ws + 131072);        // 1 KB
    float* w2    = (float*)(ws + 132096);        // 1 KB

    hipLaunchKernelGGL(prep, dim3(68), dim3(256), 0, stream, W, a1, a2, wfrag, w1, w2);
    hipLaunchKernelGGL(gat, dim3(256), dim3(1024), 0, stream,
                       seq, emb, pos, gamma, beta, w1, w2, wfrag, (float*)d_out);
}